// Round 1
// 16406.422 us; speedup vs baseline: 3.8976x; 3.8976x over previous
//
#include <hip/hip_runtime.h>
#include <hip/hip_fp16.h>
#include <cmath>

#define BDIM 64
#define TLEN 512
#define IDIM 512
#define HDIM 1024
#define ODIM 512
#define NBLK 256
#define NTHR 512

typedef _Float16 h16;
typedef _Float16 half8 __attribute__((ext_vector_type(8)));
typedef float f32x4 __attribute__((ext_vector_type(4)));

__device__ __forceinline__ float sigf(float x){ return 1.f/(1.f+__expf(-x)); }

// Activation planes (per layer): [slot 2][pl 2 (hi/lo)][bt 4][k8 32][lane 64][8] fp16.
// B-fragment-ready for mfma_f32_16x16x32_f16: element (k8, L, j) = act[b = bt*16 + (L&15)]
// [k = k8*32 + (L>>4)*8 + j].
#define PLANE_ELEMS (2*2*4*32*64*8)   // 262144 h16 per layer (512 KB)
__device__ __forceinline__ size_t poff(int slot,int pl,int bt,int k8){
    return ((((size_t)slot*2+pl)*4+bt)*32 + (size_t)k8)*512;
}

// Agent-scope (device-coherent, write-through to MALL) 2-byte store.
// sc1 = device scope on gfx940/950: the store is acked from the coherence point,
// so s_waitcnt vmcnt(0) afterwards == globally visible. No buffer_wbl2 needed.
__device__ __forceinline__ void st_h16_sc1(h16* p, h16 v){
    unsigned short b; __builtin_memcpy(&b, &v, 2);
    unsigned w = b;
    asm volatile("global_store_short %0, %1, off sc1" :: "v"(p), "v"(w) : "memory");
}

__global__ void gru_init(h16* __restrict__ planes, int* __restrict__ ctrl){
    size_t n = 2*(size_t)PLANE_ELEMS;
    for (size_t i = (size_t)blockIdx.x*blockDim.x + threadIdx.x; i < n;
         i += (size_t)gridDim.x*blockDim.x)
        planes[i] = (h16)0.f;
    if (blockIdx.x==0 && threadIdx.x<256) ctrl[threadIdx.x] = 0;  // 256 arrival flags
}

// Persistent pipelined 2-layer GRU + out-proj. 256 blocks x 512 threads, 1/CU.
// bk<128: L0-block, owns h0 units [8bk,8bk+8). bk>=128: L1-block, owns h1 units
// [8i,8i+8) and out rows [4i,4i+4), i=bk-128.
// Weights live in LDS as fp16 A-fragments: 2 m-tiles x K8 k-chunks x 64 lanes x 8.
//   tile0 = [r(u0..7) | z(u0..7)], tile1 = [n(u0..7) | out(0..3)/zeros | zeros].
// Accs split at KS8 (x/ih-part vs h/hh-part) -> n-gate and out fall out naturally.
// Phase p: L0 computes h0(p) (p<T); L1 computes h1(p-1) (1<=p<=T) and out(p-2)
// (2<=p<=T+1). One grid barrier per phase, 514 phases.
//
// Coherence scheme (replaces __threadfence + acquire-spin, which emitted a full
// buffer_wbl2 L2 flush x2/phase/block and a buffer_inv per poll iteration):
//   - h-plane stores are sc1 write-through (durable at MALL, L2 never dirtied)
//   - barrier = relaxed flag-array: block stores flags[bk]=p+1 after vmcnt(0);
//     wave 0 of every block polls all 256 flags with relaxed agent loads (>=)
//   - exactly one acquire fence (buffer_inv sc1) per wave per phase; hot-loop
//     plane loads stay PLAIN and refill L2 fresh from MALL (16-way shared/XCD)
__global__ __launch_bounds__(NTHR,1)
void gru_persist(const float* __restrict__ src,
                 const float* __restrict__ Wih0, const float* __restrict__ Whh0,
                 const float* __restrict__ bih0, const float* __restrict__ bhh0,
                 const float* __restrict__ Wih1, const float* __restrict__ Whh1,
                 const float* __restrict__ bih1, const float* __restrict__ bhh1,
                 const float* __restrict__ Wout, const float* __restrict__ bout,
                 float* __restrict__ out,
                 h16* __restrict__ h0pl, h16* __restrict__ h1pl,
                 int* __restrict__ ctrl)
{
    extern __shared__ char lds[];
    const int tid  = threadIdx.x;
    const int lane = tid & 63;
    const int wv   = __builtin_amdgcn_readfirstlane(tid >> 6);
    const int bt   = wv & 3;          // batch tile (16 b)
    const int kh2  = wv >> 2;         // k-half
    const int bk   = blockIdx.x;
    const int role = (bk >= 128);     // 0 = L0, 1 = L1
    const int ib   = role ? bk - 128 : bk;
    const int U    = 8 * ib;
    const int K8   = role ? 64 : 48;  // k8 chunks (K = 2048 / 1536)
    const int KS8  = role ? 32 : 16;  // accA/accB split (k=1024 / k=512)

    h16*   Alds = (h16*)lds;                                   // [2][K8][64][8]
    float* scr  = (float*)(lds + (size_t)2*K8*64*8*sizeof(h16)); // [4][2][2][4][64]

    // ---------------- prologue: fp32 weights -> fp16 A-fragments in LDS -------
    {
        const int t = tid >> 8;          // tile
        const int m = (tid >> 4) & 15;   // row within tile
        for (int k8 = (tid & 15); k8 < K8; k8 += 16) {
            for (int q = 0; q < 4; ++q) {
                half8 hv;
                #pragma unroll
                for (int j = 0; j < 8; ++j) {
                    const int c = k8*32 + q*8 + j;
                    float v;
                    if (!role) {
                        if (t == 1 && m >= 8) v = 0.f;
                        else {
                            int grow = (t==0) ? ((m<8)? U+m : HDIM+U+(m-8)) : (2*HDIM+U+m);
                            v = (c < IDIM) ? Wih0[(size_t)grow*IDIM + c]
                                           : Whh0[(size_t)grow*HDIM + (c-IDIM)];
                        }
                    } else {
                        if (t == 1 && m >= 8) {
                            if (m < 12) {
                                int o = 4*ib + (m-8);
                                v = (c < HDIM) ? 0.f : Wout[(size_t)o*HDIM + (c-HDIM)];
                            } else v = 0.f;
                        } else {
                            int grow = (t==0) ? ((m<8)? U+m : HDIM+U+(m-8)) : (2*HDIM+U+m);
                            v = (c < HDIM) ? Wih1[(size_t)grow*HDIM + c]
                                           : Whh1[(size_t)grow*HDIM + (c-HDIM)];
                        }
                    }
                    hv[j] = (h16)v;
                }
                *(half8*)&Alds[(((size_t)t*K8 + k8)*64 + q*16 + m)*8] = hv;
            }
        }
    }

    // per-thread epilogue identity: (unit eu, batch eb)
    const int eu = tid >> 6, eb = tid & 63;
    float br,bz,bnx,bnh;
    if (!role){ br = bih0[U+eu]+bhh0[U+eu]; bz = bih0[HDIM+U+eu]+bhh0[HDIM+U+eu];
                bnx = bih0[2*HDIM+U+eu];    bnh = bhh0[2*HDIM+U+eu]; }
    else      { br = bih1[U+eu]+bhh1[U+eu]; bz = bih1[HDIM+U+eu]+bhh1[HDIM+U+eu];
                bnx = bih1[2*HDIM+U+eu];    bnh = bhh1[2*HDIM+U+eu]; }
    float bo = 0.f;
    if (role && tid < 256) bo = bout[4*ib + (tid>>6)];
    float hprev = 0.f;

    __syncthreads();

    // Flag-array grid barrier. All per-thread sc1 data stores are vmcnt-drained
    // (== durable at MALL) before the arrival flag is stored, so a poller that
    // observes flags[b]==p+1 also observes block b's phase-p plane data.
    // Relaxed loads emit NO cache-ops; max skew across blocks is 1 phase, and
    // flags are monotone ints, so ">= p+1" is race- and wrap-free.
    auto barrier = [&](int p){
        asm volatile("s_waitcnt vmcnt(0)" ::: "memory");
        __syncthreads();
        if (wv == 0) {
            const int tgt = p + 1;
            if (lane == 0)
                __hip_atomic_store(&ctrl[bk], tgt, __ATOMIC_RELAXED, __HIP_MEMORY_SCOPE_AGENT);
            for (;;) {
                int a = __hip_atomic_load(&ctrl[lane      ], __ATOMIC_RELAXED, __HIP_MEMORY_SCOPE_AGENT);
                int b = __hip_atomic_load(&ctrl[lane +  64], __ATOMIC_RELAXED, __HIP_MEMORY_SCOPE_AGENT);
                int c = __hip_atomic_load(&ctrl[lane + 128], __ATOMIC_RELAXED, __HIP_MEMORY_SCOPE_AGENT);
                int d = __hip_atomic_load(&ctrl[lane + 192], __ATOMIC_RELAXED, __HIP_MEMORY_SCOPE_AGENT);
                if (__all((a>=tgt)&&(b>=tgt)&&(c>=tgt)&&(d>=tgt))) break;
                __builtin_amdgcn_s_sleep(2);
            }
        }
        __syncthreads();
        // one buffer_inv sc1 per wave: subsequent PLAIN plane/src loads refill
        // L1/L2 coherently from the MALL
        __builtin_amdgcn_fence(__ATOMIC_ACQUIRE, "agent");
    };

    for (int p = 0; p <= TLEN+1; ++p) {
        const bool act = role ? (p >= 1) : (p < TLEN);
        if (act) {
            f32x4 acc00 = {0.f,0.f,0.f,0.f}, acc01 = {0.f,0.f,0.f,0.f};
            f32x4 acc10 = {0.f,0.f,0.f,0.f}, acc11 = {0.f,0.f,0.f,0.f};

            // B-plane base for this wave
            const h16* BH; int koff;
            if (!role)          { BH = h0pl + poff((p-1)&1,0,bt,0); koff = 16; }
            else if (kh2 == 0)  { BH = h0pl + poff((p-1)&1,0,bt,0); koff = 0;  }
            else                { BH = h1pl + poff( p   &1,0,bt,0); koff = 32; }
            const h16* BL = BH + 65536; // pl-stride = 65536 elems

            const int k8lo = kh2 * (K8/2), k8hi = k8lo + K8/2;
            #pragma unroll 8
            for (int k8 = k8lo; k8 < k8hi; ++k8) {
                half8 bh, bl;
                if (!role && k8 < 16) {
                    // x(p): fp32 global -> hi/lo fp16 B-fragment in regs
                    const float* xp = src + ((size_t)(bt*16 + (lane&15))*TLEN + p)*IDIM
                                          + k8*32 + (lane>>4)*8;
                    float4 f0 = *(const float4*)xp;
                    float4 f1 = *(const float4*)(xp+4);
                    float f[8] = {f0.x,f0.y,f0.z,f0.w,f1.x,f1.y,f1.z,f1.w};
                    #pragma unroll
                    for (int j = 0; j < 8; ++j) {
                        h16 h = (h16)f[j];
                        bh[j] = h; bl[j] = (h16)(f[j] - (float)h);
                    }
                } else {
                    size_t o = ((size_t)(k8 - koff)*64 + lane)*8;
                    bh = *(const half8*)(BH + o);
                    bl = *(const half8*)(BL + o);
                }
                half8 a0 = *(const half8*)&Alds[(((size_t)0*K8 + k8)*64 + lane)*8];
                half8 a1 = *(const half8*)&Alds[(((size_t)1*K8 + k8)*64 + lane)*8];
                if (k8 < KS8) {
                    acc00 = __builtin_amdgcn_mfma_f32_16x16x32_f16(a0, bh, acc00, 0,0,0);
                    acc00 = __builtin_amdgcn_mfma_f32_16x16x32_f16(a0, bl, acc00, 0,0,0);
                    acc10 = __builtin_amdgcn_mfma_f32_16x16x32_f16(a1, bh, acc10, 0,0,0);
                    acc10 = __builtin_amdgcn_mfma_f32_16x16x32_f16(a1, bl, acc10, 0,0,0);
                } else {
                    acc01 = __builtin_amdgcn_mfma_f32_16x16x32_f16(a0, bh, acc01, 0,0,0);
                    acc01 = __builtin_amdgcn_mfma_f32_16x16x32_f16(a0, bl, acc01, 0,0,0);
                    acc11 = __builtin_amdgcn_mfma_f32_16x16x32_f16(a1, bh, acc11, 0,0,0);
                    acc11 = __builtin_amdgcn_mfma_f32_16x16x32_f16(a1, bl, acc11, 0,0,0);
                }
            }

            // cross-wave (k-half) reduction via LDS scratch
            if (kh2 == 1) {
                #pragma unroll
                for (int r = 0; r < 4; ++r) {
                    scr[(((bt*2+0)*2+0)*4+r)*64 + lane] = acc00[r];
                    scr[(((bt*2+0)*2+1)*4+r)*64 + lane] = acc01[r];
                    scr[(((bt*2+1)*2+0)*4+r)*64 + lane] = acc10[r];
                    scr[(((bt*2+1)*2+1)*4+r)*64 + lane] = acc11[r];
                }
            }
            __syncthreads();
            if (kh2 == 0) {
                #pragma unroll
                for (int r = 0; r < 4; ++r) {
                    scr[(((bt*2+0)*2+0)*4+r)*64 + lane] += acc00[r];
                    scr[(((bt*2+0)*2+1)*4+r)*64 + lane] += acc01[r];
                    scr[(((bt*2+1)*2+0)*4+r)*64 + lane] += acc10[r];
                    scr[(((bt*2+1)*2+1)*4+r)*64 + lane] += acc11[r];
                }
            }
            __syncthreads();

            // ---- gate epilogue: thread (eu, eb) -> D rows (r: eu, z: 8+eu, n: eu) ----
            {
                const int bte = eb>>4, le = eb&15, lq = eu>>2, rr = eu&3;
                auto rdv = [&](int t,int ab,int q)->float{
                    return scr[(((bte*2+t)*2+ab)*4+rr)*64 + q*16 + le];
                };
                float rv = rdv(0,0,lq)   + rdv(0,1,lq)   + br;
                float zv = rdv(0,0,2+lq) + rdv(0,1,2+lq) + bz;
                float nx = rdv(1,0,lq) + bnx;
                float nh = rdv(1,1,lq) + bnh;
                float r = sigf(rv), z = sigf(zv);
                float n = tanhf(nx + r*nh);
                float h = (1.f - z)*n + z*hprev;
                if (!role || p <= TLEN) {
                    hprev = h;
                    h16 hh = (h16)h;
                    h16 hl = (h16)(h - (float)hh);
                    const int uu = U + eu;
                    const int slot = (!role) ? (p&1) : ((p-1)&1);
                    h16* base = (!role) ? h0pl : h1pl;
                    size_t o = poff(slot, 0, eb>>4, uu>>5)
                             + (size_t)(((uu>>3)&3)*16 + (eb&15))*8 + (uu&7);
                    st_h16_sc1(base + o,         hh);
                    st_h16_sc1(base + o + 65536, hl);   // pl-stride
                }
            }
            // ---- out(p-2): T1 accB rows 8..11 ---- (plain cached store; write-only,
            // flushed by kernel-end writeback; never re-read -> no coherence needed)
            if (role && p >= 2 && tid < 256) {
                const int ro = tid >> 6, b = tid & 63;
                float v = scr[((((b>>4)*2+1)*2+1)*4 + ro)*64 + 32 + (b&15)] + bo;
                out[((size_t)(p-2)*BDIM + b)*ODIM + (4*ib + ro)] = v;
            }
        }
        barrier(p);
    }
}

extern "C" void kernel_launch(void* const* d_in, const int* in_sizes, int n_in,
                              void* d_out, int out_size, void* d_ws, size_t ws_size,
                              hipStream_t stream)
{
    const float* src  = (const float*)d_in[0];
    // d_in[1] = target, unused
    const float* Wih0 = (const float*)d_in[2];
    const float* Whh0 = (const float*)d_in[3];
    const float* bih0 = (const float*)d_in[4];
    const float* bhh0 = (const float*)d_in[5];
    const float* Wih1 = (const float*)d_in[6];
    const float* Whh1 = (const float*)d_in[7];
    const float* bih1 = (const float*)d_in[8];
    const float* bhh1 = (const float*)d_in[9];
    const float* Wout = (const float*)d_in[10];
    const float* bout = (const float*)d_in[11];
    float* out = (float*)d_out;

    // ws: h0 planes (512 KB) | h1 planes (512 KB) | ctrl (256 flag ints, 1 KB)
    h16* h0pl = (h16*)d_ws;
    h16* h1pl = h0pl + PLANE_ELEMS;
    int* ctrl = (int*)((char*)d_ws + 2*(size_t)PLANE_ELEMS*sizeof(h16));

    // L1 blocks need 128 KB weights + 16 KB scratch = 144 KB dynamic LDS
    const int ldsBytes = 2*64*64*8*2 + 4*2*2*4*64*4;   // 131072 + 16384 = 147456
    (void)hipFuncSetAttribute((const void*)gru_persist,
                              hipFuncAttributeMaxDynamicSharedMemorySize, ldsBytes);

    hipLaunchKernelGGL(gru_init, dim3(256), dim3(256), 0, stream, h0pl, ctrl);
    hipLaunchKernelGGL(gru_persist, dim3(NBLK), dim3(NTHR), ldsBytes, stream,
                       src, Wih0, Whh0, bih0, bhh0, Wih1, Whh1, bih1, bhh1,
                       Wout, bout, out, h0pl, h1pl, ctrl);
}

// Round 2
// 8357.769 us; speedup vs baseline: 7.6511x; 1.9630x over previous
//
#include <hip/hip_runtime.h>
#include <hip/hip_fp16.h>
#include <cmath>

#define BDIM 64
#define TLEN 512
#define IDIM 512
#define HDIM 1024
#define ODIM 512
#define NBLK 256
#define NTHR 512
#define PF 8

typedef _Float16 h16;
typedef _Float16 half8 __attribute__((ext_vector_type(8)));
typedef float f32x4 __attribute__((ext_vector_type(4)));

__device__ __forceinline__ float sigf(float x){ return 1.f/(1.f+__expf(-x)); }

// Activation planes (per layer): [slot 2][pl 2 (hi/lo)][bt 4][k8 32][lane 64][8] fp16.
#define PLANE_ELEMS (2*2*4*32*64*8)   // 262144 h16 per layer (512 KB)
__device__ __forceinline__ size_t poff(int slot,int pl,int bt,int k8){
    return ((((size_t)slot*2+pl)*4+bt)*32 + (size_t)k8)*512;
}

// Agent-scope write-through 16B store (durable at MALL after vmcnt(0)).
__device__ __forceinline__ void st_b128_sc1(void* p, f32x4 v){
    asm volatile("global_store_dwordx4 %0, %1, off sc1" :: "v"(p), "v"(v) : "memory");
}

__global__ void gru_init(h16* __restrict__ planes, int* __restrict__ ctrl){
    size_t n = 2*(size_t)PLANE_ELEMS;
    for (size_t i = (size_t)blockIdx.x*blockDim.x + threadIdx.x; i < n;
         i += (size_t)gridDim.x*blockDim.x)
        planes[i] = (h16)0.f;
    if (blockIdx.x==0 && threadIdx.x<256) ctrl[threadIdx.x] = 0;  // 256 arrival flags
}

// Persistent pipelined 2-layer GRU + out-proj. 256 blocks x 512 threads, 1/CU.
// bk<128: L0-block (h0 units [8bk,8bk+8)); bk>=128: L1-block (h1 units + out rows).
// Coherence: h-plane stores sc1 write-through; flag-array barrier with relaxed
// agent polls; ONE buffer_inv per block per phase (wave 0, completion-waited)
// so the 32 blocks/XCD share freshly-fetched plane lines in L2.
// Inner loop: hand-pipelined, PF=8 iterations of (bh,bl) prefetch in flight
// (compiler alone kept only ~2-3 loads outstanding -> latency-bound at 40 VGPRs).
__global__ __launch_bounds__(NTHR,1)
void gru_persist(const float* __restrict__ src,
                 const float* __restrict__ Wih0, const float* __restrict__ Whh0,
                 const float* __restrict__ bih0, const float* __restrict__ bhh0,
                 const float* __restrict__ Wih1, const float* __restrict__ Whh1,
                 const float* __restrict__ bih1, const float* __restrict__ bhh1,
                 const float* __restrict__ Wout, const float* __restrict__ bout,
                 float* __restrict__ out,
                 h16* __restrict__ h0pl, h16* __restrict__ h1pl,
                 int* __restrict__ ctrl)
{
    extern __shared__ char lds[];
    const int tid  = threadIdx.x;
    const int lane = tid & 63;
    const int wv   = __builtin_amdgcn_readfirstlane(tid >> 6);
    const int bt   = wv & 3;          // batch tile (16 b)
    const int kh2  = wv >> 2;         // k-half
    const int bk   = blockIdx.x;
    const int role = (bk >= 128);     // 0 = L0, 1 = L1
    const int ib   = role ? bk - 128 : bk;
    const int U    = 8 * ib;
    const int K8   = role ? 64 : 48;  // k8 chunks (K = 2048 / 1536)

    h16*   Alds = (h16*)lds;                                     // [2][K8][64][8]
    float* scr  = (float*)(lds + (size_t)2*K8*64*8*sizeof(h16)); // [4][2][2][4][64]
    h16*   hstg = (h16*)(lds + (size_t)2*K8*64*8*sizeof(h16) + 16384); // [2][4][16][8]

    // ---------------- prologue: fp32 weights -> fp16 A-fragments in LDS -------
    {
        const int t = tid >> 8;          // tile
        const int m = (tid >> 4) & 15;   // row within tile
        for (int k8 = (tid & 15); k8 < K8; k8 += 16) {
            for (int q = 0; q < 4; ++q) {
                half8 hv;
                #pragma unroll
                for (int j = 0; j < 8; ++j) {
                    const int c = k8*32 + q*8 + j;
                    float v;
                    if (!role) {
                        if (t == 1 && m >= 8) v = 0.f;
                        else {
                            int grow = (t==0) ? ((m<8)? U+m : HDIM+U+(m-8)) : (2*HDIM+U+m);
                            v = (c < IDIM) ? Wih0[(size_t)grow*IDIM + c]
                                           : Whh0[(size_t)grow*HDIM + (c-IDIM)];
                        }
                    } else {
                        if (t == 1 && m >= 8) {
                            if (m < 12) {
                                int o = 4*ib + (m-8);
                                v = (c < HDIM) ? 0.f : Wout[(size_t)o*HDIM + (c-HDIM)];
                            } else v = 0.f;
                        } else {
                            int grow = (t==0) ? ((m<8)? U+m : HDIM+U+(m-8)) : (2*HDIM+U+m);
                            v = (c < HDIM) ? Wih1[(size_t)grow*HDIM + c]
                                           : Whh1[(size_t)grow*HDIM + (c-HDIM)];
                        }
                    }
                    hv[j] = (h16)v;
                }
                *(half8*)&Alds[(((size_t)t*K8 + k8)*64 + q*16 + m)*8] = hv;
            }
        }
    }

    // per-thread epilogue identity: (unit eu, batch eb)
    const int eu = tid >> 6, eb = tid & 63;
    float br,bz,bnx,bnh;
    if (!role){ br = bih0[U+eu]+bhh0[U+eu]; bz = bih0[HDIM+U+eu]+bhh0[HDIM+U+eu];
                bnx = bih0[2*HDIM+U+eu];    bnh = bhh0[2*HDIM+U+eu]; }
    else      { br = bih1[U+eu]+bhh1[U+eu]; bz = bih1[HDIM+U+eu]+bhh1[HDIM+U+eu];
                bnx = bih1[2*HDIM+U+eu];    bnh = bhh1[2*HDIM+U+eu]; }
    float bo = 0.f;
    if (role && tid < 256) bo = bout[4*ib + (tid>>6)];
    float hprev = 0.f;

    __syncthreads();

    // Flag-array grid barrier; single acquire fence (buffer_inv) per BLOCK,
    // completion-waited in wave 0 before the closing __syncthreads.
    auto barrier = [&](int p){
        asm volatile("s_waitcnt vmcnt(0)" ::: "memory");
        __syncthreads();
        if (wv == 0) {
            const int tgt = p + 1;
            if (lane == 0)
                __hip_atomic_store(&ctrl[bk], tgt, __ATOMIC_RELAXED, __HIP_MEMORY_SCOPE_AGENT);
            for (;;) {
                int a = __hip_atomic_load(&ctrl[lane      ], __ATOMIC_RELAXED, __HIP_MEMORY_SCOPE_AGENT);
                int b = __hip_atomic_load(&ctrl[lane +  64], __ATOMIC_RELAXED, __HIP_MEMORY_SCOPE_AGENT);
                int c = __hip_atomic_load(&ctrl[lane + 128], __ATOMIC_RELAXED, __HIP_MEMORY_SCOPE_AGENT);
                int d = __hip_atomic_load(&ctrl[lane + 192], __ATOMIC_RELAXED, __HIP_MEMORY_SCOPE_AGENT);
                if (__all((a>=tgt)&&(b>=tgt)&&(c>=tgt)&&(d>=tgt))) break;
                __builtin_amdgcn_s_sleep(2);
            }
            // one buffer_inv for the whole block; wait for it to retire so the
            // other waves' post-barrier loads can't hit stale L1/L2 lines
            __builtin_amdgcn_fence(__ATOMIC_ACQUIRE, "agent");
            asm volatile("s_waitcnt vmcnt(0)" ::: "memory");
        }
        __syncthreads();
    };

    for (int p = 0; p <= TLEN+1; ++p) {
        const bool act = role ? (p >= 1) : (p < TLEN);
        if (act) {
            f32x4 acc00 = {0.f,0.f,0.f,0.f}, acc01 = {0.f,0.f,0.f,0.f};
            f32x4 acc10 = {0.f,0.f,0.f,0.f}, acc11 = {0.f,0.f,0.f,0.f};

            // ---- hand-pipelined inner loops (PF iterations of loads in flight) ----
            auto planeLoop = [&](int lo, int hi, int koff2,
                                 const h16* BHp, const h16* BLp,
                                 f32x4& aX0, f32x4& aX1){
                half8 bufH[PF], bufL[PF];
                #pragma unroll
                for (int i = 0; i < PF; ++i) {
                    size_t o = ((size_t)(lo + i - koff2)*64 + lane)*8;
                    bufH[i] = *(const half8*)(BHp + o);
                    bufL[i] = *(const half8*)(BLp + o);
                }
                for (int base = lo; base < hi; base += PF) {
                    #pragma unroll
                    for (int i = 0; i < PF; ++i) {
                        const int k8 = base + i;
                        half8 bh = bufH[i], bl = bufL[i];
                        if (k8 + PF < hi) {
                            size_t o = ((size_t)(k8 + PF - koff2)*64 + lane)*8;
                            bufH[i] = *(const half8*)(BHp + o);
                            bufL[i] = *(const half8*)(BLp + o);
                        }
                        half8 a0 = *(const half8*)&Alds[(((size_t)0*K8 + k8)*64 + lane)*8];
                        half8 a1 = *(const half8*)&Alds[(((size_t)1*K8 + k8)*64 + lane)*8];
                        aX0 = __builtin_amdgcn_mfma_f32_16x16x32_f16(a0, bh, aX0, 0,0,0);
                        aX0 = __builtin_amdgcn_mfma_f32_16x16x32_f16(a0, bl, aX0, 0,0,0);
                        aX1 = __builtin_amdgcn_mfma_f32_16x16x32_f16(a1, bh, aX1, 0,0,0);
                        aX1 = __builtin_amdgcn_mfma_f32_16x16x32_f16(a1, bl, aX1, 0,0,0);
                    }
                }
            };
            auto srcLoop = [&](f32x4& aX0, f32x4& aX1){
                const float* xb = src + ((size_t)(bt*16 + (lane&15))*TLEN + p)*IDIM
                                      + (lane>>4)*8;
                float4 f0[PF], f1[PF];
                #pragma unroll
                for (int i = 0; i < PF; ++i) {
                    f0[i] = *(const float4*)(xb + i*32);
                    f1[i] = *(const float4*)(xb + i*32 + 4);
                }
                for (int base = 0; base < 16; base += PF) {
                    #pragma unroll
                    for (int i = 0; i < PF; ++i) {
                        const int k8 = base + i;
                        float ff[8] = {f0[i].x,f0[i].y,f0[i].z,f0[i].w,
                                       f1[i].x,f1[i].y,f1[i].z,f1[i].w};
                        half8 bh, bl;
                        #pragma unroll
                        for (int j = 0; j < 8; ++j) {
                            h16 hv = (h16)ff[j];
                            bh[j] = hv; bl[j] = (h16)(ff[j] - (float)hv);
                        }
                        if (k8 + PF < 16) {
                            f0[i] = *(const float4*)(xb + (k8+PF)*32);
                            f1[i] = *(const float4*)(xb + (k8+PF)*32 + 4);
                        }
                        half8 a0 = *(const half8*)&Alds[(((size_t)0*K8 + k8)*64 + lane)*8];
                        half8 a1 = *(const half8*)&Alds[(((size_t)1*K8 + k8)*64 + lane)*8];
                        aX0 = __builtin_amdgcn_mfma_f32_16x16x32_f16(a0, bh, aX0, 0,0,0);
                        aX0 = __builtin_amdgcn_mfma_f32_16x16x32_f16(a0, bl, aX0, 0,0,0);
                        aX1 = __builtin_amdgcn_mfma_f32_16x16x32_f16(a1, bh, aX1, 0,0,0);
                        aX1 = __builtin_amdgcn_mfma_f32_16x16x32_f16(a1, bl, aX1, 0,0,0);
                    }
                }
            };

            // acc routing: L0: k8<16 (x-part) -> accA, k8>=16 (h-part) -> accB.
            //              L1: k8<32 (h0-part) -> accA, k8>=32 (h1-part) -> accB.
            if (!role) {
                const h16* BH = h0pl + poff((p-1)&1,0,bt,0);
                const h16* BL = BH + 65536;
                if (kh2 == 0) { srcLoop(acc00, acc10); planeLoop(16,24,16,BH,BL,acc01,acc11); }
                else          { planeLoop(24,48,16,BH,BL,acc01,acc11); }
            } else {
                if (kh2 == 0) { const h16* BH = h0pl + poff((p-1)&1,0,bt,0);
                                planeLoop(0,32,0,BH,BH+65536,acc00,acc10); }
                else          { const h16* BH = h1pl + poff( p   &1,0,bt,0);
                                planeLoop(32,64,32,BH,BH+65536,acc01,acc11); }
            }

            // cross-wave (k-half) reduction via LDS scratch
            if (kh2 == 1) {
                #pragma unroll
                for (int r = 0; r < 4; ++r) {
                    scr[(((bt*2+0)*2+0)*4+r)*64 + lane] = acc00[r];
                    scr[(((bt*2+0)*2+1)*4+r)*64 + lane] = acc01[r];
                    scr[(((bt*2+1)*2+0)*4+r)*64 + lane] = acc10[r];
                    scr[(((bt*2+1)*2+1)*4+r)*64 + lane] = acc11[r];
                }
            }
            __syncthreads();
            if (kh2 == 0) {
                #pragma unroll
                for (int r = 0; r < 4; ++r) {
                    scr[(((bt*2+0)*2+0)*4+r)*64 + lane] += acc00[r];
                    scr[(((bt*2+0)*2+1)*4+r)*64 + lane] += acc01[r];
                    scr[(((bt*2+1)*2+0)*4+r)*64 + lane] += acc10[r];
                    scr[(((bt*2+1)*2+1)*4+r)*64 + lane] += acc11[r];
                }
            }
            __syncthreads();

            // ---- gate epilogue: thread (eu, eb) -> h for unit U+eu, batch eb ----
            const bool doh = (!role || p <= TLEN);
            {
                const int bte = eb>>4, le = eb&15, lq = eu>>2, rr = eu&3;
                auto rdv = [&](int t,int ab,int q)->float{
                    return scr[(((bte*2+t)*2+ab)*4+rr)*64 + q*16 + le];
                };
                float rv = rdv(0,0,lq)   + rdv(0,1,lq)   + br;
                float zv = rdv(0,0,2+lq) + rdv(0,1,2+lq) + bz;
                float nx = rdv(1,0,lq) + bnx;
                float nh = rdv(1,1,lq) + bnh;
                float r = sigf(rv), z = sigf(zv);
                float n = tanhf(nx + r*nh);
                float h = (1.f - z)*n + z*hprev;
                if (doh) {
                    hprev = h;
                    h16 hh = (h16)h;
                    h16 hl = (h16)(h - (float)hh);
                    // stage into LDS: [pl][bt][le][j=eu]
                    hstg[((0*4 + (eb>>4))*16 + (eb&15))*8 + eu] = hh;
                    hstg[((1*4 + (eb>>4))*16 + (eb&15))*8 + eu] = hl;
                }
            }
            // ---- out(p-2): T1 accB rows 8..11 (plain cached store, write-only) ----
            if (role && p >= 2 && tid < 256) {
                const int ro = tid >> 6, b = tid & 63;
                float v = scr[((((b>>4)*2+1)*2+1)*4 + ro)*64 + 32 + (b&15)] + bo;
                out[((size_t)(p-2)*BDIM + b)*ODIM + (4*ib + ro)] = v;
            }
            __syncthreads();
            // ---- coalesced plane store: 128 threads x 16B sc1 dwordx4 ----
            if (doh && tid < 128) {
                const int pl = tid >> 6, bts = (tid >> 4) & 3, le = tid & 15;
                const int slot = (!role) ? (p&1) : ((p-1)&1);
                h16* basep = (!role) ? h0pl : h1pl;
                size_t g = poff(slot, pl, bts, U>>5) + (size_t)(((U>>3)&3)*16 + le)*8;
                f32x4 v = *(f32x4*)&hstg[(((size_t)pl*4 + bts)*16 + le)*8];
                st_b128_sc1(basep + g, v);
            }
        }
        barrier(p);
    }
}

extern "C" void kernel_launch(void* const* d_in, const int* in_sizes, int n_in,
                              void* d_out, int out_size, void* d_ws, size_t ws_size,
                              hipStream_t stream)
{
    const float* src  = (const float*)d_in[0];
    // d_in[1] = target, unused
    const float* Wih0 = (const float*)d_in[2];
    const float* Whh0 = (const float*)d_in[3];
    const float* bih0 = (const float*)d_in[4];
    const float* bhh0 = (const float*)d_in[5];
    const float* Wih1 = (const float*)d_in[6];
    const float* Whh1 = (const float*)d_in[7];
    const float* bih1 = (const float*)d_in[8];
    const float* bhh1 = (const float*)d_in[9];
    const float* Wout = (const float*)d_in[10];
    const float* bout = (const float*)d_in[11];
    float* out = (float*)d_out;

    // ws: h0 planes (512 KB) | h1 planes (512 KB) | ctrl (256 flag ints)
    h16* h0pl = (h16*)d_ws;
    h16* h1pl = h0pl + PLANE_ELEMS;
    int* ctrl = (int*)((char*)d_ws + 2*(size_t)PLANE_ELEMS*sizeof(h16));

    // L1 blocks: 128 KB weights + 16 KB scratch + 2 KB h-staging = 149504 B
    const int ldsBytes = 2*64*64*8*2 + 4*2*2*4*64*4 + 2*4*16*8*2;
    (void)hipFuncSetAttribute((const void*)gru_persist,
                              hipFuncAttributeMaxDynamicSharedMemorySize, ldsBytes);

    hipLaunchKernelGGL(gru_init, dim3(256), dim3(256), 0, stream, h0pl, ctrl);
    hipLaunchKernelGGL(gru_persist, dim3(NBLK), dim3(NTHR), ldsBytes, stream,
                       src, Wih0, Whh0, bih0, bhh0, Wih1, Whh1, bih1, bhh1,
                       Wout, bout, out, h0pl, h1pl, ctrl);
}

// Round 3
// 7033.184 us; speedup vs baseline: 9.0921x; 1.1883x over previous
//
#include <hip/hip_runtime.h>
#include <hip/hip_fp16.h>
#include <cmath>

#define BDIM 64
#define TLEN 512
#define IDIM 512
#define HDIM 1024
#define ODIM 512
#define NBLK 256
#define NTHR 512
#define PF 8

typedef _Float16 h16;
typedef _Float16 half8 __attribute__((ext_vector_type(8)));
typedef float f32x4 __attribute__((ext_vector_type(4)));

__device__ __forceinline__ float sigf(float x){ return 1.f/(1.f+__expf(-x)); }

// Activation planes (per layer): [slot 2][pl 2 (hi/lo)][bt 4][k8 32][lane 64][8] fp16.
#define PLANE_ELEMS (2*2*4*32*64*8)   // 262144 h16 per layer (512 KB)
__device__ __forceinline__ size_t poff(int slot,int pl,int bt,int k8){
    return ((((size_t)slot*2+pl)*4+bt)*32 + (size_t)k8)*512;
}

// Agent-scope write-through 16B store (durable at MALL after vmcnt(0)).
__device__ __forceinline__ void st_b128_sc1(void* p, f32x4 v){
    asm volatile("global_store_dwordx4 %0, %1, off sc1" :: "v"(p), "v"(v) : "memory");
}

// Counted-vmcnt wait + scheduler fence (rule #18: keep consumers below the wait).
__device__ __forceinline__ void wait_vm(int n){
    if      (n<=0)  asm volatile("s_waitcnt vmcnt(0)");
    else if (n==2)  asm volatile("s_waitcnt vmcnt(2)");
    else if (n==4)  asm volatile("s_waitcnt vmcnt(4)");
    else if (n==6)  asm volatile("s_waitcnt vmcnt(6)");
    else if (n==8)  asm volatile("s_waitcnt vmcnt(8)");
    else if (n==10) asm volatile("s_waitcnt vmcnt(10)");
    else if (n==12) asm volatile("s_waitcnt vmcnt(12)");
    else            asm volatile("s_waitcnt vmcnt(14)");
    __builtin_amdgcn_sched_barrier(0);
}

__global__ void gru_init(h16* __restrict__ planes, int* __restrict__ ctrl){
    size_t n = 2*(size_t)PLANE_ELEMS;
    for (size_t i = (size_t)blockIdx.x*blockDim.x + threadIdx.x; i < n;
         i += (size_t)gridDim.x*blockDim.x)
        planes[i] = (h16)0.f;
    if (blockIdx.x==0 && threadIdx.x<256) ctrl[threadIdx.x] = 0;  // 256 arrival flags
}

// Persistent pipelined 2-layer GRU + out-proj. 256 blocks x 512 threads, 1/CU.
// bk<128: L0-block (h0 units [8bk,8bk+8)); bk>=128: L1-block (h1 units + out rows).
// Coherence: NO cache invalidation anywhere. h-plane stores are sc1 write-through
// (durable at MALL); h-plane LOADS are sc1 read-through (device scope, same
// mechanism as the barrier flags). src/weights/out stay plain -> L2-cached
// across all 514 phases. Inner loop: inline-asm sc1 loads in a PF=8 ring with
// manual counted vmcnt(14) waits -> 16 loads/wave truly in flight (the plain-
// load version collapsed to VGPR=68, i.e. ~2 outstanding).
__global__ __launch_bounds__(NTHR,1)
void gru_persist(const float* __restrict__ src,
                 const float* __restrict__ Wih0, const float* __restrict__ Whh0,
                 const float* __restrict__ bih0, const float* __restrict__ bhh0,
                 const float* __restrict__ Wih1, const float* __restrict__ Whh1,
                 const float* __restrict__ bih1, const float* __restrict__ bhh1,
                 const float* __restrict__ Wout, const float* __restrict__ bout,
                 float* __restrict__ out,
                 h16* __restrict__ h0pl, h16* __restrict__ h1pl,
                 int* __restrict__ ctrl)
{
    extern __shared__ char lds[];
    const int tid  = threadIdx.x;
    const int lane = tid & 63;
    const int wv   = __builtin_amdgcn_readfirstlane(tid >> 6);
    const int bt   = wv & 3;          // batch tile (16 b)
    const int kh2  = wv >> 2;         // k-half
    const int bk   = blockIdx.x;
    const int role = (bk >= 128);     // 0 = L0, 1 = L1
    const int ib   = role ? bk - 128 : bk;
    const int U    = 8 * ib;
    const int K8   = role ? 64 : 48;  // k8 chunks (K = 2048 / 1536)

    h16*   Alds = (h16*)lds;                                     // [2][K8][64][8]
    float* scr  = (float*)(lds + (size_t)2*K8*64*8*sizeof(h16)); // [4][2][2][4][64]
    h16*   hstg = (h16*)(lds + (size_t)2*K8*64*8*sizeof(h16) + 16384); // [2][4][16][8]

    // ---------------- prologue: fp32 weights -> fp16 A-fragments in LDS -------
    {
        const int t = tid >> 8;          // tile
        const int m = (tid >> 4) & 15;   // row within tile
        for (int k8 = (tid & 15); k8 < K8; k8 += 16) {
            for (int q = 0; q < 4; ++q) {
                half8 hv;
                #pragma unroll
                for (int j = 0; j < 8; ++j) {
                    const int c = k8*32 + q*8 + j;
                    float v;
                    if (!role) {
                        if (t == 1 && m >= 8) v = 0.f;
                        else {
                            int grow = (t==0) ? ((m<8)? U+m : HDIM+U+(m-8)) : (2*HDIM+U+m);
                            v = (c < IDIM) ? Wih0[(size_t)grow*IDIM + c]
                                           : Whh0[(size_t)grow*HDIM + (c-IDIM)];
                        }
                    } else {
                        if (t == 1 && m >= 8) {
                            if (m < 12) {
                                int o = 4*ib + (m-8);
                                v = (c < HDIM) ? 0.f : Wout[(size_t)o*HDIM + (c-HDIM)];
                            } else v = 0.f;
                        } else {
                            int grow = (t==0) ? ((m<8)? U+m : HDIM+U+(m-8)) : (2*HDIM+U+m);
                            v = (c < HDIM) ? Wih1[(size_t)grow*HDIM + c]
                                           : Whh1[(size_t)grow*HDIM + (c-HDIM)];
                        }
                    }
                    hv[j] = (h16)v;
                }
                *(half8*)&Alds[(((size_t)t*K8 + k8)*64 + q*16 + m)*8] = hv;
            }
        }
    }

    // per-thread epilogue identity: (unit eu, batch eb)
    const int eu = tid >> 6, eb = tid & 63;
    float br,bz,bnx,bnh;
    if (!role){ br = bih0[U+eu]+bhh0[U+eu]; bz = bih0[HDIM+U+eu]+bhh0[HDIM+U+eu];
                bnx = bih0[2*HDIM+U+eu];    bnh = bhh0[2*HDIM+U+eu]; }
    else      { br = bih1[U+eu]+bhh1[U+eu]; bz = bih1[HDIM+U+eu]+bhh1[HDIM+U+eu];
                bnx = bih1[2*HDIM+U+eu];    bnh = bhh1[2*HDIM+U+eu]; }
    float bo = 0.f;
    if (role && tid < 256) bo = bout[4*ib + (tid>>6)];
    float hprev = 0.f;

    __syncthreads();

    // Flag-array grid barrier. sc1 data stores are vmcnt-drained (durable at
    // MALL) before the arrival flag; pollers use relaxed agent loads (sc1
    // read-through) so NO acquire fence / L2 invalidation is needed anywhere.
    auto barrier = [&](int p){
        asm volatile("s_waitcnt vmcnt(0)" ::: "memory");
        __syncthreads();
        if (wv == 0) {
            const int tgt = p + 1;
            if (lane == 0)
                __hip_atomic_store(&ctrl[bk], tgt, __ATOMIC_RELAXED, __HIP_MEMORY_SCOPE_AGENT);
            for (;;) {
                int a = __hip_atomic_load(&ctrl[lane      ], __ATOMIC_RELAXED, __HIP_MEMORY_SCOPE_AGENT);
                int b = __hip_atomic_load(&ctrl[lane +  64], __ATOMIC_RELAXED, __HIP_MEMORY_SCOPE_AGENT);
                int c = __hip_atomic_load(&ctrl[lane + 128], __ATOMIC_RELAXED, __HIP_MEMORY_SCOPE_AGENT);
                int d = __hip_atomic_load(&ctrl[lane + 192], __ATOMIC_RELAXED, __HIP_MEMORY_SCOPE_AGENT);
                if (__all((a>=tgt)&&(b>=tgt)&&(c>=tgt)&&(d>=tgt))) break;
                __builtin_amdgcn_s_sleep(2);
            }
        }
        __syncthreads();
    };

    for (int p = 0; p <= TLEN+1; ++p) {
        const bool act = role ? (p >= 1) : (p < TLEN);
        if (act) {
            f32x4 acc00 = {0.f,0.f,0.f,0.f}, acc01 = {0.f,0.f,0.f,0.f};
            f32x4 acc10 = {0.f,0.f,0.f,0.f}, acc11 = {0.f,0.f,0.f,0.f};

            // ---- plane loop: asm sc1 loads, PF-deep ring, counted vmcnt ----
            // BHp/BLp in half8 units; slot offset = (k8-koff2)*64+lane.
            auto planeLoop = [&](int lo, int hi, int koff2,
                                 const half8* BHp, const half8* BLp,
                                 f32x4& aX0, f32x4& aX1){
                half8 bufH[PF], bufL[PF];
                asm volatile("s_waitcnt vmcnt(0)" ::: "memory"); // zero the count
                #pragma unroll
                for (int i = 0; i < PF; ++i) {
                    size_t o = (size_t)(lo + i - koff2)*64 + lane;
                    asm volatile("global_load_dwordx4 %0, %1, off sc1"
                                 : "=v"(bufH[i]) : "v"(BHp + o));
                    asm volatile("global_load_dwordx4 %0, %1, off sc1"
                                 : "=v"(bufL[i]) : "v"(BLp + o));
                }
                int base;
                for (base = lo; base + PF < hi; base += PF) {
                    #pragma unroll
                    for (int i = 0; i < PF; ++i) {
                        const int k8 = base + i;
                        wait_vm(2*PF-2);      // slot i's pair retired
                        half8 a0 = *(const half8*)&Alds[(((size_t)0*K8 + k8)*64 + lane)*8];
                        half8 a1 = *(const half8*)&Alds[(((size_t)1*K8 + k8)*64 + lane)*8];
                        aX0 = __builtin_amdgcn_mfma_f32_16x16x32_f16(a0, bufH[i], aX0, 0,0,0);
                        aX0 = __builtin_amdgcn_mfma_f32_16x16x32_f16(a0, bufL[i], aX0, 0,0,0);
                        aX1 = __builtin_amdgcn_mfma_f32_16x16x32_f16(a1, bufH[i], aX1, 0,0,0);
                        aX1 = __builtin_amdgcn_mfma_f32_16x16x32_f16(a1, bufL[i], aX1, 0,0,0);
                        // refill slot i (new SSA values; old ones stay live in regs)
                        size_t o = (size_t)(k8 + PF - koff2)*64 + lane;
                        asm volatile("global_load_dwordx4 %0, %1, off sc1"
                                     : "=v"(bufH[i]) : "v"(BHp + o));
                        asm volatile("global_load_dwordx4 %0, %1, off sc1"
                                     : "=v"(bufL[i]) : "v"(BLp + o));
                    }
                }
                // tail batch: ring full on entry, decreasing waits
                #pragma unroll
                for (int i = 0; i < PF; ++i) {
                    const int k8 = base + i;
                    wait_vm(2*(PF-1-i));
                    half8 a0 = *(const half8*)&Alds[(((size_t)0*K8 + k8)*64 + lane)*8];
                    half8 a1 = *(const half8*)&Alds[(((size_t)1*K8 + k8)*64 + lane)*8];
                    aX0 = __builtin_amdgcn_mfma_f32_16x16x32_f16(a0, bufH[i], aX0, 0,0,0);
                    aX0 = __builtin_amdgcn_mfma_f32_16x16x32_f16(a0, bufL[i], aX0, 0,0,0);
                    aX1 = __builtin_amdgcn_mfma_f32_16x16x32_f16(a1, bufH[i], aX1, 0,0,0);
                    aX1 = __builtin_amdgcn_mfma_f32_16x16x32_f16(a1, bufL[i], aX1, 0,0,0);
                }
            };
            // src is immutable -> plain cached loads (L2 stays warm: no invs).
            auto srcLoop = [&](f32x4& aX0, f32x4& aX1){
                const float* xb = src + ((size_t)(bt*16 + (lane&15))*TLEN + p)*IDIM
                                      + (lane>>4)*8;
                float4 f0[PF], f1[PF];
                #pragma unroll
                for (int i = 0; i < PF; ++i) {
                    f0[i] = *(const float4*)(xb + i*32);
                    f1[i] = *(const float4*)(xb + i*32 + 4);
                }
                for (int base = 0; base < 16; base += PF) {
                    #pragma unroll
                    for (int i = 0; i < PF; ++i) {
                        const int k8 = base + i;
                        float ff[8] = {f0[i].x,f0[i].y,f0[i].z,f0[i].w,
                                       f1[i].x,f1[i].y,f1[i].z,f1[i].w};
                        half8 bh, bl;
                        #pragma unroll
                        for (int j = 0; j < 8; ++j) {
                            h16 hv = (h16)ff[j];
                            bh[j] = hv; bl[j] = (h16)(ff[j] - (float)hv);
                        }
                        if (k8 + PF < 16) {
                            f0[i] = *(const float4*)(xb + (k8+PF)*32);
                            f1[i] = *(const float4*)(xb + (k8+PF)*32 + 4);
                        }
                        half8 a0 = *(const half8*)&Alds[(((size_t)0*K8 + k8)*64 + lane)*8];
                        half8 a1 = *(const half8*)&Alds[(((size_t)1*K8 + k8)*64 + lane)*8];
                        aX0 = __builtin_amdgcn_mfma_f32_16x16x32_f16(a0, bh, aX0, 0,0,0);
                        aX0 = __builtin_amdgcn_mfma_f32_16x16x32_f16(a0, bl, aX0, 0,0,0);
                        aX1 = __builtin_amdgcn_mfma_f32_16x16x32_f16(a1, bh, aX1, 0,0,0);
                        aX1 = __builtin_amdgcn_mfma_f32_16x16x32_f16(a1, bl, aX1, 0,0,0);
                    }
                }
            };

            // acc routing: L0: k8<16 (x-part) -> accA, k8>=16 (h-part) -> accB.
            //              L1: k8<32 (h0-part) -> accA, k8>=32 (h1-part) -> accB.
            if (!role) {
                const half8* BH = (const half8*)(h0pl + poff((p-1)&1,0,bt,0));
                const half8* BL = BH + 8192;   // pl-stride = 65536 h16 = 8192 half8
                if (kh2 == 0) { srcLoop(acc00, acc10); planeLoop(16,24,16,BH,BL,acc01,acc11); }
                else          { planeLoop(24,48,16,BH,BL,acc01,acc11); }
            } else {
                if (kh2 == 0) { const half8* BH = (const half8*)(h0pl + poff((p-1)&1,0,bt,0));
                                planeLoop(0,32,0,BH,BH+8192,acc00,acc10); }
                else          { const half8* BH = (const half8*)(h1pl + poff( p   &1,0,bt,0));
                                planeLoop(32,64,32,BH,BH+8192,acc01,acc11); }
            }

            // cross-wave (k-half) reduction via LDS scratch
            if (kh2 == 1) {
                #pragma unroll
                for (int r = 0; r < 4; ++r) {
                    scr[(((bt*2+0)*2+0)*4+r)*64 + lane] = acc00[r];
                    scr[(((bt*2+0)*2+1)*4+r)*64 + lane] = acc01[r];
                    scr[(((bt*2+1)*2+0)*4+r)*64 + lane] = acc10[r];
                    scr[(((bt*2+1)*2+1)*4+r)*64 + lane] = acc11[r];
                }
            }
            __syncthreads();
            if (kh2 == 0) {
                #pragma unroll
                for (int r = 0; r < 4; ++r) {
                    scr[(((bt*2+0)*2+0)*4+r)*64 + lane] += acc00[r];
                    scr[(((bt*2+0)*2+1)*4+r)*64 + lane] += acc01[r];
                    scr[(((bt*2+1)*2+0)*4+r)*64 + lane] += acc10[r];
                    scr[(((bt*2+1)*2+1)*4+r)*64 + lane] += acc11[r];
                }
            }
            __syncthreads();

            // ---- gate epilogue: thread (eu, eb) -> h for unit U+eu, batch eb ----
            const bool doh = (!role || p <= TLEN);
            {
                const int bte = eb>>4, le = eb&15, lq = eu>>2, rr = eu&3;
                auto rdv = [&](int t,int ab,int q)->float{
                    return scr[(((bte*2+t)*2+ab)*4+rr)*64 + q*16 + le];
                };
                float rv = rdv(0,0,lq)   + rdv(0,1,lq)   + br;
                float zv = rdv(0,0,2+lq) + rdv(0,1,2+lq) + bz;
                float nx = rdv(1,0,lq) + bnx;
                float nh = rdv(1,1,lq) + bnh;
                float r = sigf(rv), z = sigf(zv);
                float n = tanhf(nx + r*nh);
                float h = (1.f - z)*n + z*hprev;
                if (doh) {
                    hprev = h;
                    h16 hh = (h16)h;
                    h16 hl = (h16)(h - (float)hh);
                    // stage into LDS: [pl][bt][le][j=eu]
                    hstg[((0*4 + (eb>>4))*16 + (eb&15))*8 + eu] = hh;
                    hstg[((1*4 + (eb>>4))*16 + (eb&15))*8 + eu] = hl;
                }
            }
            // ---- out(p-2): T1 accB rows 8..11 (plain cached store, write-only) ----
            if (role && p >= 2 && tid < 256) {
                const int ro = tid >> 6, b = tid & 63;
                float v = scr[((((b>>4)*2+1)*2+1)*4 + ro)*64 + 32 + (b&15)] + bo;
                out[((size_t)(p-2)*BDIM + b)*ODIM + (4*ib + ro)] = v;
            }
            __syncthreads();
            // ---- coalesced plane store: 128 threads x 16B sc1 dwordx4 ----
            if (doh && tid < 128) {
                const int pl = tid >> 6, bts = (tid >> 4) & 3, le = tid & 15;
                const int slot = (!role) ? (p&1) : ((p-1)&1);
                h16* basep = (!role) ? h0pl : h1pl;
                size_t g = poff(slot, pl, bts, U>>5) + (size_t)(((U>>3)&3)*16 + le)*8;
                f32x4 v = *(f32x4*)&hstg[(((size_t)pl*4 + bts)*16 + le)*8];
                st_b128_sc1(basep + g, v);
            }
        }
        barrier(p);
    }
}

extern "C" void kernel_launch(void* const* d_in, const int* in_sizes, int n_in,
                              void* d_out, int out_size, void* d_ws, size_t ws_size,
                              hipStream_t stream)
{
    const float* src  = (const float*)d_in[0];
    // d_in[1] = target, unused
    const float* Wih0 = (const float*)d_in[2];
    const float* Whh0 = (const float*)d_in[3];
    const float* bih0 = (const float*)d_in[4];
    const float* bhh0 = (const float*)d_in[5];
    const float* Wih1 = (const float*)d_in[6];
    const float* Whh1 = (const float*)d_in[7];
    const float* bih1 = (const float*)d_in[8];
    const float* bhh1 = (const float*)d_in[9];
    const float* Wout = (const float*)d_in[10];
    const float* bout = (const float*)d_in[11];
    float* out = (float*)d_out;

    // ws: h0 planes (512 KB) | h1 planes (512 KB) | ctrl (256 flag ints)
    h16* h0pl = (h16*)d_ws;
    h16* h1pl = h0pl + PLANE_ELEMS;
    int* ctrl = (int*)((char*)d_ws + 2*(size_t)PLANE_ELEMS*sizeof(h16));

    // L1 blocks: 128 KB weights + 16 KB scratch + 2 KB h-staging = 149504 B
    const int ldsBytes = 2*64*64*8*2 + 4*2*2*4*64*4 + 2*4*16*8*2;
    (void)hipFuncSetAttribute((const void*)gru_persist,
                              hipFuncAttributeMaxDynamicSharedMemorySize, ldsBytes);

    hipLaunchKernelGGL(gru_init, dim3(256), dim3(256), 0, stream, h0pl, ctrl);
    hipLaunchKernelGGL(gru_persist, dim3(NBLK), dim3(NTHR), ldsBytes, stream,
                       src, Wih0, Whh0, bih0, bhh0, Wih1, Whh1, bih1, bhh1,
                       Wout, bout, out, h0pl, h1pl, ctrl);
}